// Round 4
// baseline (311.461 us; speedup 1.0000x reference)
//
#include <hip/hip_runtime.h>

#define KF 128        // feature dim
#define NSUP 256      // support points per species
#define NSPEC 4
#define TA 64         // atom tile
#define NB_MAIN 768   // persistent main-kernel grid (3 blocks/CU x 256 CU)

typedef __bf16 bf16x8 __attribute__((ext_vector_type(8)));
typedef __bf16 bf16x4 __attribute__((ext_vector_type(4)));
typedef float  f32x4  __attribute__((ext_vector_type(4)));

// ---------------- species histogram ----------------

__global__ void k_count(const int* __restrict__ sp, int n, int* __restrict__ counts) {
    __shared__ int h[NSPEC];
    if (threadIdx.x < NSPEC) h[threadIdx.x] = 0;
    __syncthreads();
    for (int i = blockIdx.x * blockDim.x + threadIdx.x; i < n; i += gridDim.x * blockDim.x)
        atomicAdd(&h[sp[i]], 1);
    __syncthreads();
    if (threadIdx.x < NSPEC) atomicAdd(&counts[threadIdx.x], h[threadIdx.x]);
}

// ---------------- scatter (offsets computed locally) + fused support prep ----------------
// Blocks [0, SB): bucket-scatter atom indices. Blocks [SB, SB+64): convert support
// to fragment-major bf16: [species][coltile 0..15][kstep 0..3][lane 0..63][8 bf16],
// lane l supplies B col = ct*16 + (l&15), k = kk*32 + (l>>4)*8 .. +7.

__global__ void k_scatter_prep(const int* __restrict__ sp, int n,
                               const int* __restrict__ counts, int* __restrict__ cursors,
                               int* __restrict__ order,
                               const float* __restrict__ sup, __bf16* __restrict__ outb,
                               int SB)
{
    if ((int)blockIdx.x >= SB) {
        int t = ((int)blockIdx.x - SB) * 256 + (int)threadIdx.x;
        if (t < NSPEC * 16 * 4 * 64) {
            int lane = t & 63;
            int kk   = (t >> 6) & 3;
            int ct   = (t >> 8) & 15;
            int s    = t >> 12;
            int m  = ct * 16 + (lane & 15);
            int k0 = kk * 32 + (lane >> 4) * 8;
            const float* src = sup + ((size_t)(s * NSUP + m)) * KF + k0;
            bf16x8 v;
            #pragma unroll
            for (int j = 0; j < 8; ++j) v[j] = (__bf16)src[j];
            *(bf16x8*)(outb + (size_t)t * 8) = v;
        }
        return;
    }
    __shared__ int lh[NSPEC];
    __shared__ int basep[NSPEC];
    if (threadIdx.x < NSPEC) lh[threadIdx.x] = 0;
    __syncthreads();
    int i = blockIdx.x * 256 + threadIdx.x;
    int s = (i < n) ? sp[i] : -1;
    int local = 0;
    if (s >= 0) local = atomicAdd(&lh[s], 1);
    __syncthreads();
    if (threadIdx.x < NSPEC) {
        int q = threadIdx.x;
        int off = 0;
        for (int r = 0; r < q; ++r) off += counts[r];
        basep[q] = off + atomicAdd(&cursors[q], lh[q]);
    }
    __syncthreads();
    if (s >= 0) order[basep[s] + local] = i;
}

// ---------------- persistent pipelined MFMA kernel ----------------

#define TILEINFO(T, S, OFF, BASE, REM) do {                         \
    int _loc = (T); int _cc;                                        \
    if (_loc < nb0)        { S = 0; OFF = 0;  _cc = c0; }           \
    else { _loc -= nb0;                                             \
      if (_loc < nb1)      { S = 1; OFF = o1; _cc = c1; }           \
      else { _loc -= nb1;                                           \
        if (_loc < nb2)    { S = 2; OFF = o2; _cc = c2; }           \
        else { _loc -= nb2;  S = 3; OFF = o3; _cc = c3; } } }       \
    BASE = _loc * TA; REM = _cc - BASE; if (REM > TA) REM = TA;     \
} while (0)

__global__ __launch_bounds__(256, 3) void k_main(
    const float* __restrict__ ps,
    const __bf16* __restrict__ sup_frag,
    const float* __restrict__ weights,
    const int* __restrict__ sids,
    float* __restrict__ out,
    const int* __restrict__ counts,
    const int* __restrict__ order)
{
    __shared__ __align__(16) char ldsA[TA * 256];   // 64 rows x 128 bf16, XOR-swizzled
    __shared__ float nrm[2][TA];
    __shared__ float accW[2][4][TA];
    __shared__ int   idx_sh[2][TA];

    const int tid  = threadIdx.x;
    const int lane = tid & 63, w = tid >> 6;
    const int lrow = lane & 15, lk = lane >> 4;

    const int c0 = counts[0], c1 = counts[1], c2 = counts[2], c3 = counts[3];
    const int nb0 = (c0 + TA - 1) / TA, nb1 = (c1 + TA - 1) / TA,
              nb2 = (c2 + TA - 1) / TA, nb3 = (c3 + TA - 1) / TA;
    const int o1 = c0, o2 = c0 + c1, o3 = c0 + c1 + c2;
    const int ntot = nb0 + nb1 + nb2 + nb3;

    const int t0 = blockIdx.x;
    float4 pf[8];
    int myidx = -1;
    int p = 0;

    // ---- prologue: indices + row prefetch for first tile ----
    if (t0 < ntot && tid < TA) {
        int s, off, base, rem;
        TILEINFO(t0, s, off, base, rem);
        myidx = (tid < rem) ? order[off + base + tid] : -1;
        idx_sh[0][tid] = myidx;
    }
    __syncthreads();
    if (t0 < ntot) {
        #pragma unroll
        for (int it = 0; it < 8; ++it) {
            int flat = it * 256 + tid, row = flat >> 5, c = flat & 31;
            int a = idx_sh[0][row];
            pf[it] = (a >= 0) ? *(const float4*)(ps + (size_t)a * KF + c * 4)
                              : make_float4(0.f, 0.f, 0.f, 0.f);
        }
    }

    for (int t = t0; t < ntot; t += NB_MAIN, p ^= 1) {
        int s, off, base, rem;
        TILEINFO(t, s, off, base, rem);
        const int tn = t + NB_MAIN;

        // issue next tile's index loads (in flight under the write phase)
        int ivn = -1;
        if (tid < TA && tn < ntot) {
            int s2, off2, base2, rem2;
            TILEINFO(tn, s2, off2, base2, rem2);
            if (tid < rem2) ivn = order[off2 + base2 + tid];
        }

        // ---- write phase: regs -> bf16 LDS (swizzled) + fp32 row norms ----
        #pragma unroll
        for (int it = 0; it < 8; ++it) {
            int flat = it * 256 + tid, row = flat >> 5, c = flat & 31;
            float4 v = pf[it];
            bf16x4 bv;
            bv[0] = (__bf16)v.x; bv[1] = (__bf16)v.y; bv[2] = (__bf16)v.z; bv[3] = (__bf16)v.w;
            *(bf16x4*)(ldsA + row * 256 + ((c * 8) ^ ((row & 7) << 4))) = bv;
            float sm = v.x * v.x + v.y * v.y + v.z * v.z + v.w * v.w;
            #pragma unroll
            for (int m = 1; m < 32; m <<= 1) sm += __shfl_xor(sm, m, 32);
            if ((tid & 31) == 0) nrm[p][row] = sm;
        }
        if (tid < TA) idx_sh[p ^ 1][tid] = ivn;
        __syncthreads();   // B1: ldsA, nrm[p], idx_sh[p^1] ready

        // ---- issue next tile's row prefetch (covered by compute below) ----
        if (tn < ntot) {
            #pragma unroll
            for (int it = 0; it < 8; ++it) {
                int flat = it * 256 + tid, row = flat >> 5, c = flat & 31;
                int a = idx_sh[p ^ 1][row];
                pf[it] = (a >= 0) ? *(const float4*)(ps + (size_t)a * KF + c * 4)
                                  : make_float4(0.f, 0.f, 0.f, 0.f);
            }
        }

        // ---- compute phase ----
        float wreg[4];
        #pragma unroll
        for (int ct = 0; ct < 4; ++ct)
            wreg[ct] = weights[s * NSUP + (w * 4 + ct) * 16 + lrow];

        f32x4 acc[4][4];
        #pragma unroll
        for (int i = 0; i < 4; ++i)
            #pragma unroll
            for (int j = 0; j < 4; ++j) acc[i][j] = (f32x4){0.f, 0.f, 0.f, 0.f};

        const __bf16* bsup = sup_frag + (size_t)s * (16 * 4 * 64 * 8);

        #pragma unroll
        for (int kk = 0; kk < 4; ++kk) {
            bf16x8 afr[4];
            #pragma unroll
            for (int rt = 0; rt < 4; ++rt) {
                int row = rt * 16 + lrow;
                afr[rt] = *(const bf16x8*)(ldsA + row * 256 + ((kk * 64 + lk * 16) ^ ((row & 7) << 4)));
            }
            #pragma unroll
            for (int ct = 0; ct < 4; ++ct) {
                int ctg = w * 4 + ct;
                bf16x8 bfr = *(const bf16x8*)(bsup + ((size_t)(ctg * 4 + kk) * 64 + lane) * 8);
                #pragma unroll
                for (int rt = 0; rt < 4; ++rt)
                    acc[rt][ct] = __builtin_amdgcn_mfma_f32_16x16x32_bf16(afr[rt], bfr, acc[rt][ct], 0, 0, 0);
            }
        }

        // epilogue: per-atom partials, reduce across the 16 col-lanes
        #pragma unroll
        for (int rt = 0; rt < 4; ++rt) {
            float pj[4] = {0.f, 0.f, 0.f, 0.f};
            #pragma unroll
            for (int ct = 0; ct < 4; ++ct)
                #pragma unroll
                for (int j = 0; j < 4; ++j) {
                    float d = acc[rt][ct][j];
                    pj[j] += d * d * wreg[ct];
                }
            #pragma unroll
            for (int j = 0; j < 4; ++j) {
                float v = pj[j];
                #pragma unroll
                for (int m = 1; m < 16; m <<= 1) v += __shfl_xor(v, m, 16);
                if (lrow == 0) accW[p][w][rt * 16 + lk * 4 + j] = v;
            }
        }
        __syncthreads();   // B2: accW[p] complete; ldsA free for next write

        if (tid < TA && myidx >= 0) {
            float nn = nrm[p][tid];
            float e = accW[p][0][tid] + accW[p][1][tid] + accW[p][2][tid] + accW[p][3][tid];
            if (nn > 0.f) atomicAdd(&out[sids[myidx]], e / nn);
        }
        myidx = ivn;
    }
}

// ---------------- slow-but-correct fallback (ws too small) ----------------

__global__ void k_fallback(const float* __restrict__ ps, const float* __restrict__ support,
                           const float* __restrict__ weights, const int* __restrict__ species,
                           const int* __restrict__ struct_ids, float* __restrict__ out, int n)
{
    int gw = (blockIdx.x * blockDim.x + threadIdx.x) >> 6;
    int lane = threadIdx.x & 63;
    int nw = (gridDim.x * blockDim.x) >> 6;
    for (int atom = gw; atom < n; atom += nw) {
        const float* row = ps + (size_t)atom * KF;
        float x0 = row[lane], x1 = row[lane + 64];
        float nsum = x0 * x0 + x1 * x1;
        for (int o = 32; o; o >>= 1) nsum += __shfl_xor(nsum, o);
        float iv2 = 1.0f / nsum;
        int s = species[atom];
        const float* sup = support + (size_t)s * NSUP * KF;
        const float* w = weights + (size_t)s * NSUP;
        float e = 0.f;
        for (int mm = 0; mm < 4; ++mm) {
            int m = lane + mm * 64;
            const float* srow = sup + (size_t)m * KF;
            float d = 0.f;
            for (int k = 0; k < KF; ++k) d += row[k] * srow[k];
            e += d * d * w[m];
        }
        for (int o = 32; o; o >>= 1) e += __shfl_xor(e, o);
        if (lane == 0) atomicAdd(&out[struct_ids[atom]], e * iv2);
    }
}

// ---------------- launch ----------------

extern "C" void kernel_launch(void* const* d_in, const int* in_sizes, int n_in,
                              void* d_out, int out_size, void* d_ws, size_t ws_size,
                              hipStream_t stream)
{
    const float* ps       = (const float*)d_in[0];
    const float* support  = (const float*)d_in[1];
    const float* weights  = (const float*)d_in[2];
    const int*   species  = (const int*)d_in[3];
    const int*   sids     = (const int*)d_in[4];
    float* out = (float*)d_out;
    const int n = in_sizes[0] / KF;

    hipMemsetAsync(d_out, 0, (size_t)out_size * sizeof(float), stream);

    const size_t frag_bytes = (size_t)NSPEC * 16 * 4 * 64 * 8 * sizeof(__bf16);  // 256 KB
    size_t order_end = 64 + (size_t)n * sizeof(int);
    size_t frag_off  = (order_end + 15) & ~(size_t)15;
    const size_t need = frag_off + frag_bytes;
    if (ws_size < need) {
        k_fallback<<<2048, 256, 0, stream>>>(ps, support, weights, species, sids, out, n);
        return;
    }

    int* ws      = (int*)d_ws;
    int* counts  = ws;        // [0..3]
    int* cursors = ws + 8;    // [8..11]
    int* order   = ws + 16;
    __bf16* sup_frag = (__bf16*)((char*)d_ws + frag_off);

    hipMemsetAsync(ws, 0, 64, stream);
    k_count<<<512, 256, 0, stream>>>(species, n, counts);

    const int SB = (n + 255) / 256;
    const int PREP_BLOCKS = (NSPEC * 16 * 4 * 64 + 255) / 256;   // 64
    k_scatter_prep<<<SB + PREP_BLOCKS, 256, 0, stream>>>(species, n, counts, cursors, order,
                                                         support, sup_frag, SB);

    k_main<<<NB_MAIN, 256, 0, stream>>>(ps, sup_frag, weights, sids, out, counts, order);
}

// Round 5
// 265.502 us; speedup vs baseline: 1.1731x; 1.1731x over previous
//
#include <hip/hip_runtime.h>

#define KF 128        // feature dim
#define NSUP 256      // support points per species
#define NSPEC 4
#define TW 16         // atoms per wave-tile
#define NB_MAIN 1024  // 4 blocks/CU

typedef __bf16 bf16x8 __attribute__((ext_vector_type(8)));
typedef float  f32x4  __attribute__((ext_vector_type(4)));

// ---------------- species histogram ----------------

__global__ void k_count(const int* __restrict__ sp, int n, int* __restrict__ counts) {
    __shared__ int h[NSPEC];
    if (threadIdx.x < NSPEC) h[threadIdx.x] = 0;
    __syncthreads();
    for (int i = blockIdx.x * blockDim.x + threadIdx.x; i < n; i += gridDim.x * blockDim.x)
        atomicAdd(&h[sp[i]], 1);
    __syncthreads();
    if (threadIdx.x < NSPEC) atomicAdd(&counts[threadIdx.x], h[threadIdx.x]);
}

// ---------------- scatter + fused support prep ----------------
// Blocks [0, SB): bucket-scatter atom indices (offsets from counts prefix).
// Blocks [SB, SB+64): support -> fragment-major bf16:
// [species][ct 0..15][kk 0..3][lane 0..63][8 bf16];
// lane l supplies B col = ct*16 + (l&15), k = kk*32 + (l>>4)*8 .. +7.

__global__ void k_scatter_prep(const int* __restrict__ sp, int n,
                               const int* __restrict__ counts, int* __restrict__ cursors,
                               int* __restrict__ order,
                               const float* __restrict__ sup, __bf16* __restrict__ outb,
                               int SB)
{
    if ((int)blockIdx.x >= SB) {
        int t = ((int)blockIdx.x - SB) * 256 + (int)threadIdx.x;
        if (t < NSPEC * 16 * 4 * 64) {
            int lane = t & 63;
            int kk   = (t >> 6) & 3;
            int ct   = (t >> 8) & 15;
            int s    = t >> 12;
            int m  = ct * 16 + (lane & 15);
            int k0 = kk * 32 + (lane >> 4) * 8;
            const float* src = sup + ((size_t)(s * NSUP + m)) * KF + k0;
            bf16x8 v;
            #pragma unroll
            for (int j = 0; j < 8; ++j) v[j] = (__bf16)src[j];
            *(bf16x8*)(outb + (size_t)t * 8) = v;
        }
        return;
    }
    __shared__ int lh[NSPEC];
    __shared__ int basep[NSPEC];
    if (threadIdx.x < NSPEC) lh[threadIdx.x] = 0;
    __syncthreads();
    int i = blockIdx.x * 256 + threadIdx.x;
    int s = (i < n) ? sp[i] : -1;
    int local = 0;
    if (s >= 0) local = atomicAdd(&lh[s], 1);
    __syncthreads();
    if (threadIdx.x < NSPEC) {
        int q = threadIdx.x;
        int off = 0;
        for (int r = 0; r < q; ++r) off += counts[r];
        basep[q] = off + atomicAdd(&cursors[q], lh[q]);
    }
    __syncthreads();
    if (s >= 0) order[basep[s] + local] = i;
}

// ---------------- wave-independent MFMA kernel (no LDS, no barriers) ----------------

#define TILEINFO(T, S, OFF, BASE, REM) do {                         \
    int _loc = (T); int _cc;                                        \
    if (_loc < nb0)        { S = 0; OFF = 0;  _cc = c0; }           \
    else { _loc -= nb0;                                             \
      if (_loc < nb1)      { S = 1; OFF = o1; _cc = c1; }           \
      else { _loc -= nb1;                                           \
        if (_loc < nb2)    { S = 2; OFF = o2; _cc = c2; }           \
        else { _loc -= nb2;  S = 3; OFF = o3; _cc = c3; } } }       \
    BASE = _loc * TW; REM = _cc - BASE; if (REM > TW) REM = TW;     \
} while (0)

__global__ __launch_bounds__(256, 4) void k_main(
    const float* __restrict__ ps,
    const __bf16* __restrict__ sup_frag,
    const float* __restrict__ weights,
    const int* __restrict__ sids,
    float* __restrict__ out,
    const int* __restrict__ counts,
    const int* __restrict__ order)
{
    const int lane = threadIdx.x & 63;
    const int r = lane & 15, g = lane >> 4;     // fragment row, k-group
    const int gw = blockIdx.x * 4 + (threadIdx.x >> 6);
    const int gs = NB_MAIN * 4;

    const int c0 = counts[0], c1 = counts[1], c2 = counts[2], c3 = counts[3];
    const int nb0 = (c0 + TW - 1) / TW, nb1 = (c1 + TW - 1) / TW,
              nb2 = (c2 + TW - 1) / TW, nb3 = (c3 + TW - 1) / TW;
    const int o1 = c0, o2 = c0 + c1, o3 = c0 + c1 + c2;
    const int ntot = nb0 + nb1 + nb2 + nb3;

    int t = gw;
    if (t >= ntot) return;

    // ---- prologue: idx(t) -> gather pf(t); issue idx(t+gs) ----
    int s, off, base, rem;
    TILEINFO(t, s, off, base, rem);
    int cur_idx = (r < rem) ? order[off + base + r] : -1;

    float4 pf[8];
    #pragma unroll
    for (int it = 0; it < 8; ++it) {
        int kk = it >> 1, h = it & 1;
        pf[it] = (cur_idx >= 0)
            ? *(const float4*)(ps + (size_t)cur_idx * KF + kk * 32 + g * 8 + h * 4)
            : make_float4(0.f, 0.f, 0.f, 0.f);
    }

    int nidx = -1;
    {
        int tn = t + gs;
        if (tn < ntot) {
            int s2, off2, base2, rem2;
            TILEINFO(tn, s2, off2, base2, rem2);
            if (r < rem2) nidx = order[off2 + base2 + r];
        }
    }

    for (; t < ntot; t += gs) {
        TILEINFO(t, s, off, base, rem);
        const int tn = t + gs;

        // structure id for this tile's atom (in flight under compute)
        int cur_sid = (cur_idx >= 0) ? sids[cur_idx] : 0;

        // ---- norms (fp32) + convert to A-fragments ----
        float sm = 0.f;
        #pragma unroll
        for (int it = 0; it < 8; ++it) {
            float4 v = pf[it];
            sm += v.x * v.x + v.y * v.y + v.z * v.z + v.w * v.w;
        }
        sm += __shfl_xor(sm, 16);
        sm += __shfl_xor(sm, 32);
        const float nn = sm;   // ||row r||^2, replicated across the 4 g-lanes

        bf16x8 afr[4];
        #pragma unroll
        for (int kk = 0; kk < 4; ++kk) {
            float4 a = pf[2 * kk], b = pf[2 * kk + 1];
            bf16x8 v;
            v[0] = (__bf16)a.x; v[1] = (__bf16)a.y; v[2] = (__bf16)a.z; v[3] = (__bf16)a.w;
            v[4] = (__bf16)b.x; v[5] = (__bf16)b.y; v[6] = (__bf16)b.z; v[7] = (__bf16)b.w;
            afr[kk] = v;
        }

        // ---- issue next tile's gathers (covered by ct-loop) ----
        if (tn < ntot) {
            #pragma unroll
            for (int it = 0; it < 8; ++it) {
                int kk = it >> 1, h = it & 1;
                pf[it] = (nidx >= 0)
                    ? *(const float4*)(ps + (size_t)nidx * KF + kk * 32 + g * 8 + h * 4)
                    : make_float4(0.f, 0.f, 0.f, 0.f);
            }
        }

        // ---- issue idx(t+2gs) ----
        int nidx2 = -1;
        {
            int t2 = t + 2 * gs;
            if (t2 < ntot) {
                int s3, off3, base3, rem3;
                TILEINFO(t2, s3, off3, base3, rem3);
                if (r < rem3) nidx2 = order[off3 + base3 + r];
            }
        }

        // ---- compute: 16 col-tiles x 4 MFMA, fused d^2*w epilogue ----
        const __bf16* bsup = sup_frag + (size_t)s * (16 * 4 * 64 * 8);
        const float*  wsp  = weights + s * NSUP;
        float e0 = 0.f, e1 = 0.f, e2 = 0.f, e3 = 0.f;

        #pragma unroll
        for (int ct = 0; ct < 16; ++ct) {
            float wv = wsp[ct * 16 + r];    // weight of col = ct*16 + r
            f32x4 acc = (f32x4){0.f, 0.f, 0.f, 0.f};
            #pragma unroll
            for (int kk = 0; kk < 4; ++kk) {
                bf16x8 bfr = *(const bf16x8*)(bsup + ((size_t)(ct * 4 + kk) * 64 + lane) * 8);
                acc = __builtin_amdgcn_mfma_f32_16x16x32_bf16(afr[kk], bfr, acc, 0, 0, 0);
            }
            e0 += acc[0] * acc[0] * wv;
            e1 += acc[1] * acc[1] * wv;
            e2 += acc[2] * acc[2] * wv;
            e3 += acc[3] * acc[3] * wv;
        }

        // reduce each e_j over the 16 col-lanes (bits 0..3)
        #pragma unroll
        for (int m = 1; m < 16; m <<= 1) {
            e0 += __shfl_xor(e0, m);
            e1 += __shfl_xor(e1, m);
            e2 += __shfl_xor(e2, m);
            e3 += __shfl_xor(e3, m);
        }

        // lane (g, r) with r>>2 == g outputs row r (= g*4 + (r&3))
        if ((r >> 2) == g && cur_idx >= 0 && nn > 0.f) {
            int j = r & 3;
            float v = (j == 0) ? e0 : (j == 1) ? e1 : (j == 2) ? e2 : e3;
            atomicAdd(&out[cur_sid], v / nn);
        }

        cur_idx = nidx;
        nidx = nidx2;
    }
}

// ---------------- slow-but-correct fallback (ws too small) ----------------

__global__ void k_fallback(const float* __restrict__ ps, const float* __restrict__ support,
                           const float* __restrict__ weights, const int* __restrict__ species,
                           const int* __restrict__ struct_ids, float* __restrict__ out, int n)
{
    int gw = (blockIdx.x * blockDim.x + threadIdx.x) >> 6;
    int lane = threadIdx.x & 63;
    int nw = (gridDim.x * blockDim.x) >> 6;
    for (int atom = gw; atom < n; atom += nw) {
        const float* row = ps + (size_t)atom * KF;
        float x0 = row[lane], x1 = row[lane + 64];
        float nsum = x0 * x0 + x1 * x1;
        for (int o = 32; o; o >>= 1) nsum += __shfl_xor(nsum, o);
        float iv2 = 1.0f / nsum;
        int s = species[atom];
        const float* sup = support + (size_t)s * NSUP * KF;
        const float* w = weights + (size_t)s * NSUP;
        float e = 0.f;
        for (int mm = 0; mm < 4; ++mm) {
            int m = lane + mm * 64;
            const float* srow = sup + (size_t)m * KF;
            float d = 0.f;
            for (int k = 0; k < KF; ++k) d += row[k] * srow[k];
            e += d * d * w[m];
        }
        for (int o = 32; o; o >>= 1) e += __shfl_xor(e, o);
        if (lane == 0) atomicAdd(&out[struct_ids[atom]], e * iv2);
    }
}

// ---------------- launch ----------------

extern "C" void kernel_launch(void* const* d_in, const int* in_sizes, int n_in,
                              void* d_out, int out_size, void* d_ws, size_t ws_size,
                              hipStream_t stream)
{
    const float* ps       = (const float*)d_in[0];
    const float* support  = (const float*)d_in[1];
    const float* weights  = (const float*)d_in[2];
    const int*   species  = (const int*)d_in[3];
    const int*   sids     = (const int*)d_in[4];
    float* out = (float*)d_out;
    const int n = in_sizes[0] / KF;

    hipMemsetAsync(d_out, 0, (size_t)out_size * sizeof(float), stream);

    const size_t frag_bytes = (size_t)NSPEC * 16 * 4 * 64 * 8 * sizeof(__bf16);  // 256 KB
    size_t order_end = 64 + (size_t)n * sizeof(int);
    size_t frag_off  = (order_end + 15) & ~(size_t)15;
    const size_t need = frag_off + frag_bytes;
    if (ws_size < need) {
        k_fallback<<<2048, 256, 0, stream>>>(ps, support, weights, species, sids, out, n);
        return;
    }

    int* ws      = (int*)d_ws;
    int* counts  = ws;        // [0..3]
    int* cursors = ws + 8;    // [8..11]
    int* order   = ws + 16;
    __bf16* sup_frag = (__bf16*)((char*)d_ws + frag_off);

    hipMemsetAsync(ws, 0, 64, stream);
    k_count<<<512, 256, 0, stream>>>(species, n, counts);

    const int SB = (n + 255) / 256;
    const int PREP_BLOCKS = (NSPEC * 16 * 4 * 64 + 255) / 256;   // 64
    k_scatter_prep<<<SB + PREP_BLOCKS, 256, 0, stream>>>(species, n, counts, cursors, order,
                                                         support, sup_frag, SB);

    k_main<<<NB_MAIN, 256, 0, stream>>>(ps, sup_frag, weights, sids, out, counts, order);
}